// Round 4
// baseline (324.477 us; speedup 1.0000x reference)
//
#include <hip/hip_runtime.h>

namespace {

constexpr int Bn = 2;
constexpr int Dn = 64;
constexpr int Hn = 96;
constexpr int Wn = 96;
constexpr int HW = Hn * Wn;          // 9216
constexpr int S  = Dn * HW;          // 589824 per (vol,batch) slab
constexpr int NBS = Bn * S;          // 1179648
constexpr int NT  = 2 * NBS;         // 2359296 (slabs: predB0,predB1,truthB0,truthB1)
constexpr int WPR = Wn / 32;         // 3 words per x-row
constexpr int WPP = HW / 32;         // 288 words per z-plane
constexpr int WPS = S / 32;          // 18432 words per slab
constexpr int NTW = NT / 32;         // 73728 packed words total
constexpr float INFD = 1e12f;
constexpr float EPSf = 1e-7f;
constexpr int TPB = 256;
constexpr int BLK_NBS = NBS / TPB;   // 4608
constexpr int OPT = 8;               // EDT outputs per thread (register reuse)
constexpr int BLK_EDT = NT / OPT / TPB;  // 1152
constexpr int BLK_PER_SLAB_C = (S / Wn) * (Wn / OPT) / TPB; // 288 edt2-blocks/slab
constexpr int NITER = 10;

// ---- binarize both masks, bit-packed via ballot ----
__global__ __launch_bounds__(TPB) void k_binarize(const float* __restrict__ logits,
                                                  const int* __restrict__ labels,
                                                  unsigned* __restrict__ Mb) {
  int idx = blockIdx.x * TPB + threadIdx.x;     // over NBS
  int b = idx / S;
  int s = idx - b * S;
  float l0 = logits[(b * 2 + 0) * S + s];
  float l1 = logits[(b * 2 + 1) * S + s];
  bool vp = l1 > l0;                            // softmax(p1)>0.5 <=> l1>l0
  bool vt = labels[idx] > 0;
  unsigned long long mp = __ballot(vp);
  unsigned long long mt = __ballot(vt);
  int lane = threadIdx.x & 63;
  if (lane == 0) {
    Mb[idx >> 5]         = (unsigned)mp;
    Mb[(NBS + idx) >> 5] = (unsigned)mt;
  } else if (lane == 32) {
    Mb[idx >> 5]         = (unsigned)(mp >> 32);
    Mb[(NBS + idx) >> 5] = (unsigned)(mt >> 32);
  }
}

// ---- fused uniform skeleton step on input X:
//        E = erode(X)   (written to eout, becomes next step's X)
//        delta = X & ~dil3(E)          <-- X, not E! (R3 bug was delta = E&~dil3(E))
//        skel (|)= delta
__global__ __launch_bounds__(TPB) void k_step(const unsigned* __restrict__ x,
                                              unsigned* __restrict__ eout,
                                              unsigned* __restrict__ skel,
                                              int init) {
  constexpr int ZC = 8;                          // output planes per block
  __shared__ unsigned lx[12 * WPP];              // X planes zc-2 .. zc+9
  __shared__ unsigned le[10 * WPP];              // E planes zc-1 .. zc+8
  int slab = blockIdx.x >> 3;
  int zc = (blockIdx.x & 7) * ZC;
  int tid = threadIdx.x;
  const unsigned* xs = x + slab * WPS;
  for (int t = tid; t < 12 * WPP; t += TPB) {
    int zp = zc - 2 + t / WPP;
    lx[t] = (zp >= 0 && zp < Dn) ? xs[zp * WPP + (t % WPP)] : 0xFFFFFFFFu;
  }
  __syncthreads();
  for (int t = tid; t < 10 * WPP; t += TPB) {
    int zi = t / WPP;                            // logical z = zc-1+zi
    int z = zc - 1 + zi;
    unsigned res = 0u;                           // z-OOB E plane = 0 (dilate pad)
    if (z >= 0 && z < Dn) {
      int w = t - zi * WPP;
      int y = w / WPR, wx = w - y * WPR;
      int base = (zi + 1) * WPP + w;             // lx plane idx = z-(zc-2) = zi+1
      unsigned v = lx[base];
      unsigned l = (v << 1) | (wx > 0 ? (lx[base - 1] >> 31) : 1u);
      unsigned r = (v >> 1) | (wx < WPR - 1 ? (lx[base + 1] << 31) : 0x80000000u);
      unsigned ym = (y > 0)      ? lx[base - WPR] : 0xFFFFFFFFu;
      unsigned yp = (y < Hn - 1) ? lx[base + WPR] : 0xFFFFFFFFu;
      unsigned zm = lx[base - WPP];              // OOB z loaded as all-ones
      unsigned zq = lx[base + WPP];
      res = v & l & r & ym & yp & zm & zq;
    }
    le[t] = res;
  }
  __syncthreads();
  for (int t = tid; t < ZC * WPP; t += TPB) {
    int zi = t / WPP;
    int z = zc + zi;
    int w = t - zi * WPP;
    int y = w / WPR, wx = w - y * WPR;
    int base = (zi + 1) * WPP + w;               // le plane idx = z-(zc-1) = zi+1
    unsigned acc = 0u;
    #pragma unroll
    for (int dz = -1; dz <= 1; ++dz) {
      #pragma unroll
      for (int dy = -1; dy <= 1; ++dy) {
        if (y + dy < 0 || y + dy >= Hn) continue;
        int bb = base + dz * WPP + dy * WPR;     // le z-OOB planes are zeroed
        unsigned c = le[bb];
        unsigned p = (wx > 0)       ? le[bb - 1] : 0u;
        unsigned n = (wx < WPR - 1) ? le[bb + 1] : 0u;
        acc |= c | ((c << 1) | (p >> 31)) | ((c >> 1) | (n << 31));
      }
    }
    unsigned ex = le[base];                      // E(z) -> next x
    unsigned xv = lx[(zi + 2) * WPP + w];        // X(z): lx plane idx = z-(zc-2)
    unsigned delta = xv & ~acc;                  // THE FIX: X & ~dil3(erode(X))
    int gi = slab * WPS + z * WPP + w;
    eout[gi] = ex;
    skel[gi] = init ? delta : (skel[gi] | delta);
  }
}

// ---- EDT pass 0 (z axis, L=64): reads packed mask bits, writes d2 floats ----
__global__ __launch_bounds__(TPB) void k_edt0(const unsigned* __restrict__ Mb,
                                              float* __restrict__ out) {
  int gt = blockIdx.x * TPB + threadIdx.x;
  int c = gt % (4 * HW);                         // col: slab*9216 + s2d (lanes coalesce)
  int chunk = gt / (4 * HW);                     // 0..7
  int slab = c / HW;
  int s2d = c - slab * HW;
  int i0 = chunk * OPT;
  const unsigned* mb = Mb + slab * WPS;
  float best[OPT];
  #pragma unroll
  for (int s = 0; s < OPT; ++s) best[s] = 3.4e38f;
  float db = (float)i0;
  #pragma unroll 4
  for (int j = 0; j < Dn; ++j) {
    int bi = j * HW + s2d;
    float f = ((mb[bi >> 5] >> (bi & 31)) & 1u) ? INFD : 0.0f;
    #pragma unroll
    for (int s = 0; s < OPT; ++s) {
      float d = db + (float)s;
      best[s] = fminf(best[s], fmaf(d, d, f));
    }
    db -= 1.0f;
  }
  float* o = out + slab * S + s2d;
  #pragma unroll
  for (int s = 0; s < OPT; ++s) o[(i0 + s) * HW] = best[s];
}

// ---- EDT pass 1 (y axis, L=96) ----
__global__ __launch_bounds__(TPB) void k_edt1(const float* __restrict__ in,
                                              float* __restrict__ out) {
  int gt = blockIdx.x * TPB + threadIdx.x;
  int c = gt % (4 * Dn * Wn);                    // col: (slab,z,x), lanes coalesce
  int chunk = gt / (4 * Dn * Wn);                // 0..11
  int sz = c / Wn;                               // slab*64+z
  int x = c - sz * Wn;
  int base = sz * HW + x;
  int i0 = chunk * OPT;
  float best[OPT];
  #pragma unroll
  for (int s = 0; s < OPT; ++s) best[s] = 3.4e38f;
  float db = (float)i0;
  #pragma unroll 4
  for (int j = 0; j < Hn; ++j) {
    float f = in[base + j * Wn];
    #pragma unroll
    for (int s = 0; s < OPT; ++s) {
      float d = db + (float)s;
      best[s] = fminf(best[s], fmaf(d, d, f));
    }
    db -= 1.0f;
  }
  #pragma unroll
  for (int s = 0; s < OPT; ++s) out[base + (i0 + s) * Wn] = best[s];
}

// ---- EDT pass 2 (x axis, L=96) fused with skel-masked per-block max of d2 ----
__global__ __launch_bounds__(TPB) void k_edt2(const float* __restrict__ in,
                                              float* __restrict__ out,
                                              const unsigned* __restrict__ skel,
                                              float* __restrict__ pmax) {
  __shared__ float red[TPB];
  int gt = blockIdx.x * TPB + threadIdx.x;
  int row = gt / (Wn / OPT);                     // (slab,z,y); 12 chunks per row
  int chunk = gt - row * (Wn / OPT);
  int base = row * Wn;
  int i0 = chunk * OPT;
  float best[OPT];
  #pragma unroll
  for (int s = 0; s < OPT; ++s) best[s] = 3.4e38f;
  float db = (float)i0;
  #pragma unroll 4
  for (int j = 0; j < Wn; ++j) {
    float f = in[base + j];                      // broadcast across row's threads
    #pragma unroll
    for (int s = 0; s < OPT; ++s) {
      float d = db + (float)s;
      best[s] = fminf(best[s], fmaf(d, d, f));
    }
    db -= 1.0f;
  }
  #pragma unroll
  for (int s = 0; s < OPT; ++s) out[base + i0 + s] = best[s];
  // masked max of d2 (sqrt deferred; sqrt is monotone & applied to same value)
  unsigned wv = skel[(base + i0) >> 5] >> (i0 & 31); // base%32==0 so ok
  float m = 0.0f;
  #pragma unroll
  for (int s = 0; s < OPT; ++s)
    if ((wv >> s) & 1u) m = fmaxf(m, best[s]);
  int tid = threadIdx.x;
  red[tid] = m;
  __syncthreads();
  for (int off = TPB / 2; off > 0; off >>= 1) {
    if (tid < off) red[tid] = fmaxf(red[tid], red[tid + off]);
    __syncthreads();
  }
  if (tid == 0) pmax[blockIdx.x] = red[0];
}

// ---- stage 2: per-slab max over 288 block partials, then sqrt ----
__global__ __launch_bounds__(TPB) void k_rmax2(const float* __restrict__ pmax,
                                               float* __restrict__ rmaxf) {
  __shared__ float red[TPB];
  int tid = threadIdx.x;
  float m = 0.0f;
  const float* p = pmax + blockIdx.x * BLK_PER_SLAB_C;
  for (int i = tid; i < BLK_PER_SLAB_C; i += TPB) m = fmaxf(m, p[i]);
  red[tid] = m;
  __syncthreads();
  for (int off = TPB / 2; off > 0; off >>= 1) {
    if (tid < off) red[tid] = fmaxf(red[tid], red[tid + off]);
    __syncthreads();
  }
  if (tid == 0) rmaxf[blockIdx.x] = sqrtf(red[0]);
}

// ---- per-voxel weighted terms -> per-block double4 partials (no atomics) ----
__global__ __launch_bounds__(TPB) void k_sums1(const float* __restrict__ d2,
                                               const unsigned* __restrict__ skel,
                                               const float* __restrict__ rmaxf,
                                               double* __restrict__ ps) {
  __shared__ double red[TPB];
  int tid = threadIdx.x;
  int idx = blockIdx.x * TPB + tid;              // over NBS
  int b = idx / S;
  float rmax_p = rmaxf[b];                       // slabs: pred b0,b1, truth b0,b1
  float rmax_t = rmaxf[2 + b];
  float dist_p = sqrtf(d2[idx]);
  float dist_t = sqrtf(d2[NBS + idx]);
  bool sp = (skel[idx >> 5] >> (idx & 31)) & 1u;
  bool st = (skel[(NBS + idx) >> 5] >> (idx & 31)) & 1u;
  float q_vp = (rmax_p > 0.0f) ? dist_p / rmax_p : dist_p;
  float q_vl = (rmax_t > 0.0f) ? dist_t / rmax_t : dist_t;
  float q_spvp = sp ? q_vp : 0.0f;
  float q_slvl = st ? q_vl : 0.0f;
  float q_sp = sp ? (1.0f + EPSf) / (q_spvp * q_spvp + EPSf) : 0.0f;
  float q_sl = st ? (1.0f + EPSf) / (q_slvl * q_slvl + EPSf) : 0.0f;
  float t1 = q_sp * q_vl;
  float t2 = ((q_spvp != 0.0f) && (q_slvl == 0.0f)) ? q_spvp * q_sp : q_slvl * q_sp;
  float t3 = q_sl * q_vp;
  float t4 = ((q_slvl != 0.0f) && (q_spvp == 0.0f)) ? q_slvl * q_sl : q_spvp * q_sl;
  double terms[4] = {(double)t1, (double)t2, (double)t3, (double)t4};
  #pragma unroll
  for (int k = 0; k < 4; ++k) {
    red[tid] = terms[k];
    __syncthreads();
    for (int off = TPB / 2; off > 0; off >>= 1) {
      if (tid < off) red[tid] += red[tid + off];
      __syncthreads();
    }
    if (tid == 0) ps[blockIdx.x * 4 + k] = red[0];
    __syncthreads();
  }
}

// ---- stage 2: reduce 4608 partials per term, compute loss ----
__global__ __launch_bounds__(TPB) void k_sums2(const double* __restrict__ ps,
                                               float* __restrict__ out) {
  __shared__ double red[TPB];
  int tid = threadIdx.x;
  double s[4] = {0.0, 0.0, 0.0, 0.0};
  for (int i = tid; i < BLK_NBS; i += TPB) {
    s[0] += ps[i * 4 + 0];
    s[1] += ps[i * 4 + 1];
    s[2] += ps[i * 4 + 2];
    s[3] += ps[i * 4 + 3];
  }
  double tot[4];
  #pragma unroll
  for (int k = 0; k < 4; ++k) {
    red[tid] = s[k];
    __syncthreads();
    for (int off = TPB / 2; off > 0; off >>= 1) {
      if (tid < off) red[tid] += red[tid + off];
      __syncthreads();
    }
    if (tid == 0) tot[k] = red[0];
    __syncthreads();
  }
  if (tid == 0) {
    double wp = (tot[0] + 1.0) / (tot[1] + 1.0);
    double ws = (tot[2] + 1.0) / (tot[3] + 1.0);
    out[0] = (float)(1.0 - 2.0 * (wp * ws) / (wp + ws));
  }
}

} // namespace

extern "C" void kernel_launch(void* const* d_in, const int* in_sizes, int n_in,
                              void* d_out, int out_size, void* d_ws, size_t ws_size,
                              hipStream_t stream) {
  (void)in_sizes; (void)n_in; (void)out_size; (void)ws_size;
  const float* logits = (const float*)d_in[0];   // [B,2,D,H,W] f32
  const int* labels   = (const int*)d_in[1];     // [B,1,D,H,W] i32
  float* out = (float*)d_out;

  // workspace: 2 float volumes + 4 packed bit volumes + partials
  float* D2 = (float*)d_ws;                 // EDT ping
  float* EF = D2 + NT;                      // EDT pong
  unsigned* MB    = (unsigned*)(EF + NT);   // pristine masks (EDT source)
  unsigned* XB    = MB + NTW;               // skeleton x ping
  unsigned* EB    = XB + NTW;               // skeleton x pong
  unsigned* SKELB = EB + NTW;
  float* PMAX  = (float*)(SKELB + NTW);     // 1152 per-block d2 maxes
  double* PS   = (double*)(PMAX + BLK_EDT); // 4608*4 doubles (8B-aligned offset)
  float* RMAXF = (float*)(PS + 4 * BLK_NBS);

  dim3 blk(TPB);

  k_binarize<<<BLK_NBS, blk, 0, stream>>>(logits, labels, MB);

  // ---- soft skeleton: 11 fused uniform steps (init + 10 iters), MB preserved ----
  k_step<<<32, blk, 0, stream>>>(MB, XB, SKELB, 1);
  unsigned* a = XB;
  unsigned* bb = EB;
  for (int it = 0; it < NITER; ++it) {
    k_step<<<32, blk, 0, stream>>>(a, bb, SKELB, 0);
    unsigned* t = a; a = bb; bb = t;
  }

  // ---- exact EDT: 3 register-blocked min-conv passes ----
  k_edt0<<<BLK_EDT, blk, 0, stream>>>(MB, D2);
  k_edt1<<<BLK_EDT, blk, 0, stream>>>(D2, EF);
  k_edt2<<<BLK_EDT, blk, 0, stream>>>(EF, D2, SKELB, PMAX);

  // ---- rmax stage 2, weighted sums, loss ----
  k_rmax2<<<4, blk, 0, stream>>>(PMAX, RMAXF);
  k_sums1<<<BLK_NBS, blk, 0, stream>>>(D2, SKELB, RMAXF, PS);
  k_sums2<<<1, blk, 0, stream>>>(PS, out);
}

// Round 5
// 182.584 us; speedup vs baseline: 1.7771x; 1.7771x over previous
//
#include <hip/hip_runtime.h>

namespace {

constexpr int Bn = 2;
constexpr int Dn = 64;
constexpr int Hn = 96;
constexpr int Wn = 96;
constexpr int HW = Hn * Wn;          // 9216
constexpr int S  = Dn * HW;          // 589824 per (vol,batch) slab
constexpr int NBS = Bn * S;          // 1179648
constexpr int NT  = 2 * NBS;         // 2359296 (slabs: predB0,predB1,truthB0,truthB1)
constexpr int WPR = Wn / 32;         // 3 words per x-row
constexpr int WPP = HW / 32;         // 288 words per z-plane
constexpr int WPS = S / 32;          // 18432 words per slab
constexpr float INFD = 1e12f;
constexpr float EPSf = 1e-7f;
constexpr int TPB = 256;
constexpr int BLK_NBS = NBS / TPB;   // 4608
constexpr int OPT = 8;               // EDT outputs per thread (register reuse)
constexpr int BLK_EDT = NT / OPT / TPB;  // 1152
constexpr int BLK_PER_SLAB_C = (S / Wn) * (Wn / OPT) / TPB; // 288 edt2-blocks/slab
constexpr int BLK_SUMS = NBS / 4 / TPB;  // 1152 (4 voxels per thread)

// ---- binarize both masks, bit-packed via ballot ----
__global__ __launch_bounds__(TPB) void k_binarize(const float* __restrict__ logits,
                                                  const int* __restrict__ labels,
                                                  unsigned* __restrict__ Mb) {
  int idx = blockIdx.x * TPB + threadIdx.x;     // over NBS
  int b = idx / S;
  int s = idx - b * S;
  float l0 = logits[(b * 2 + 0) * S + s];
  float l1 = logits[(b * 2 + 1) * S + s];
  bool vp = l1 > l0;                            // softmax(p1)>0.5 <=> l1>l0
  bool vt = labels[idx] > 0;
  unsigned long long mp = __ballot(vp);
  unsigned long long mt = __ballot(vt);
  int lane = threadIdx.x & 63;
  if (lane == 0) {
    Mb[idx >> 5]         = (unsigned)mp;
    Mb[(NBS + idx) >> 5] = (unsigned)mt;
  } else if (lane == 32) {
    Mb[idx >> 5]         = (unsigned)(mp >> 32);
    Mb[(NBS + idx) >> 5] = (unsigned)(mt >> 32);
  }
}

// erode one word from LDS array A (plane stride WPP), center at A+pb+w.
// In-plane OOB (y,x) pads with 1s; z-halo must be present in A.
__device__ __forceinline__ unsigned erode_w(const unsigned* A, int pb, int w,
                                            int y, int wx) {
  unsigned v = A[pb + w];
  unsigned l = (v << 1) | (wx > 0       ? (A[pb + w - 1] >> 31) : 1u);
  unsigned r = (v >> 1) | (wx < WPR - 1 ? (A[pb + w + 1] << 31) : 0x80000000u);
  unsigned ym = (y > 0)      ? A[pb + w - WPR] : 0xFFFFFFFFu;
  unsigned yp = (y < Hn - 1) ? A[pb + w + WPR] : 0xFFFFFFFFu;
  unsigned zm = A[pb - WPP + w];
  unsigned zp = A[pb + WPP + w];
  return v & l & r & ym & yp & zm & zp;
}

// 3x3x3 dilate one word from LDS array A; center plane index pc (logical z);
// logical-z OOB planes contribute 0 (dilate pad), y/x OOB contribute 0.
__device__ __forceinline__ unsigned dil3_w(const unsigned* A, int pc, int z,
                                           int w, int y, int wx) {
  unsigned acc = 0u;
  #pragma unroll
  for (int dz = -1; dz <= 1; ++dz) {
    if (z + dz < 0 || z + dz >= Dn) continue;
    int base = (pc + dz) * WPP + w;
    #pragma unroll
    for (int dy = -1; dy <= 1; ++dy) {
      if (y + dy < 0 || y + dy >= Hn) continue;
      int bb = base + dy * WPR;
      unsigned c = A[bb];
      unsigned p = (wx > 0)       ? A[bb - 1] : 0u;
      unsigned n = (wx < WPR - 1) ? A[bb + 1] : 0u;
      acc |= c | ((c << 1) | (p >> 31)) | ((c >> 1) | (n << 31));
    }
  }
  return acc;
}

// ---- fused skeleton step(s), one output plane per block (256 blocks).
// NUP=2: from X do two reference updates:
//   E = erode(X); E2 = erode(E)
//   skel (|)= (X & ~dil3(E)) | (E & ~dil3(E2));  next X = E2
// NUP=1: one update: skel (|)= X & ~dil3(E); next X = E.
template <int NUP>
__global__ __launch_bounds__(TPB) void k_stepN(const unsigned* __restrict__ x,
                                               unsigned* __restrict__ eout,
                                               unsigned* __restrict__ skel,
                                               int init) {
  constexpr int XH = NUP + 1;                  // X z-halo
  constexpr int XP = 2 * XH + 1;               // X planes (NUP=2:7, NUP=1:5)
  constexpr int EP = 2 * NUP + 1;              // E planes (5 / 3)
  __shared__ unsigned lx[XP * WPP];
  __shared__ unsigned le[EP * WPP];
  __shared__ unsigned le2[(NUP == 2 ? 3 : 1) * WPP];
  int slab = blockIdx.x >> 6;
  int z = blockIdx.x & 63;
  int tid = threadIdx.x;
  const unsigned* xs = x + slab * WPS;

  // load X planes z-XH .. z+XH (logical OOB -> all-ones: erode pad)
  for (int t = tid; t < XP * WPP; t += TPB) {
    int zp = z - XH + t / WPP;
    lx[t] = (zp >= 0 && zp < Dn) ? xs[zp * WPP + (t % WPP)] : 0xFFFFFFFFu;
  }
  __syncthreads();

  // E planes logical z-NUP .. z+NUP  (le index ei <-> lx index ei+1)
  for (int t = tid; t < EP * WPP; t += TPB) {
    int ei = t / WPP;
    int w = t - ei * WPP;
    int y = w / WPR, wx = w - y * WPR;
    le[t] = erode_w(lx, (ei + 1) * WPP, w, y, wx);
  }
  __syncthreads();

  if constexpr (NUP == 2) {
    // E2 planes logical z-1 .. z+1  (le2 index j <-> le index j+1)
    for (int t = tid; t < 3 * WPP; t += TPB) {
      int j = t / WPP;
      int w = t - j * WPP;
      int y = w / WPR, wx = w - y * WPR;
      le2[t] = erode_w(le, (j + 1) * WPP, w, y, wx);
    }
    __syncthreads();
  }

  // output plane z
  for (int t = tid; t < WPP; t += TPB) {
    int w = t;
    int y = w / WPR, wx = w - y * WPR;
    unsigned accE = dil3_w(le, NUP, z, w, y, wx);
    unsigned xv = lx[XH * WPP + w];              // X at z
    unsigned sk = xv & ~accE;
    unsigned ex;
    if constexpr (NUP == 2) {
      unsigned accE2 = dil3_w(le2, 1, z, w, y, wx);
      unsigned ev = le[NUP * WPP + w];           // E at z
      sk |= ev & ~accE2;
      ex = le2[1 * WPP + w];                     // E2 at z -> next X
    } else {
      ex = le[NUP * WPP + w];                    // E at z -> next X
    }
    int gi = slab * WPS + z * WPP + w;
    eout[gi] = ex;
    skel[gi] = init ? sk : (skel[gi] | sk);
  }
}

// ---- EDT pass 0 (z axis, L=64): reads packed mask bits, writes d2 floats ----
__global__ __launch_bounds__(TPB) void k_edt0(const unsigned* __restrict__ Mb,
                                              float* __restrict__ out) {
  int gt = blockIdx.x * TPB + threadIdx.x;
  int c = gt % (4 * HW);                         // col: slab*9216 + s2d
  int chunk = gt / (4 * HW);                     // 0..7
  int slab = c / HW;
  int s2d = c - slab * HW;
  int i0 = chunk * OPT;
  const unsigned* mb = Mb + slab * WPS;
  float best[OPT];
  #pragma unroll
  for (int s = 0; s < OPT; ++s) best[s] = 3.4e38f;
  float db = (float)i0;
  #pragma unroll 4
  for (int j = 0; j < Dn; ++j) {
    int bi = j * HW + s2d;
    float f = ((mb[bi >> 5] >> (bi & 31)) & 1u) ? INFD : 0.0f;
    #pragma unroll
    for (int s = 0; s < OPT; ++s) {
      float d = db + (float)s;
      best[s] = fminf(best[s], fmaf(d, d, f));
    }
    db -= 1.0f;
  }
  float* o = out + slab * S + s2d;
  #pragma unroll
  for (int s = 0; s < OPT; ++s) o[(i0 + s) * HW] = best[s];
}

// ---- EDT pass 1 (y axis, L=96) ----
__global__ __launch_bounds__(TPB) void k_edt1(const float* __restrict__ in,
                                              float* __restrict__ out) {
  int gt = blockIdx.x * TPB + threadIdx.x;
  int c = gt % (4 * Dn * Wn);                    // col: (slab,z,x)
  int chunk = gt / (4 * Dn * Wn);                // 0..11
  int sz = c / Wn;
  int x = c - sz * Wn;
  int base = sz * HW + x;
  int i0 = chunk * OPT;
  float best[OPT];
  #pragma unroll
  for (int s = 0; s < OPT; ++s) best[s] = 3.4e38f;
  float db = (float)i0;
  #pragma unroll 4
  for (int j = 0; j < Hn; ++j) {
    float f = in[base + j * Wn];
    #pragma unroll
    for (int s = 0; s < OPT; ++s) {
      float d = db + (float)s;
      best[s] = fminf(best[s], fmaf(d, d, f));
    }
    db -= 1.0f;
  }
  #pragma unroll
  for (int s = 0; s < OPT; ++s) out[base + (i0 + s) * Wn] = best[s];
}

// ---- EDT pass 2 (x axis, L=96) fused with skel-masked per-block max of d2 ----
__global__ __launch_bounds__(TPB) void k_edt2(const float* __restrict__ in,
                                              float* __restrict__ out,
                                              const unsigned* __restrict__ skel,
                                              float* __restrict__ pmax) {
  __shared__ float red[TPB];
  int gt = blockIdx.x * TPB + threadIdx.x;
  int row = gt / (Wn / OPT);                     // (slab,z,y); 12 chunks per row
  int chunk = gt - row * (Wn / OPT);
  int base = row * Wn;
  int i0 = chunk * OPT;
  float best[OPT];
  #pragma unroll
  for (int s = 0; s < OPT; ++s) best[s] = 3.4e38f;
  float db = (float)i0;
  #pragma unroll 4
  for (int j = 0; j < Wn; ++j) {
    float f = in[base + j];
    #pragma unroll
    for (int s = 0; s < OPT; ++s) {
      float d = db + (float)s;
      best[s] = fminf(best[s], fmaf(d, d, f));
    }
    db -= 1.0f;
  }
  #pragma unroll
  for (int s = 0; s < OPT; ++s) out[base + i0 + s] = best[s];
  unsigned wv = skel[(base + i0) >> 5] >> (i0 & 31);
  float m = 0.0f;
  #pragma unroll
  for (int s = 0; s < OPT; ++s)
    if ((wv >> s) & 1u) m = fmaxf(m, best[s]);
  int tid = threadIdx.x;
  red[tid] = m;
  __syncthreads();
  for (int off = TPB / 2; off > 0; off >>= 1) {
    if (tid < off) red[tid] = fmaxf(red[tid], red[tid + off]);
    __syncthreads();
  }
  if (tid == 0) pmax[blockIdx.x] = red[0];
}

// ---- stage 2: per-slab max over 288 block partials, then sqrt ----
__global__ __launch_bounds__(TPB) void k_rmax2(const float* __restrict__ pmax,
                                               float* __restrict__ rmaxf) {
  __shared__ float red[TPB];
  int tid = threadIdx.x;
  float m = 0.0f;
  const float* p = pmax + blockIdx.x * BLK_PER_SLAB_C;
  for (int i = tid; i < BLK_PER_SLAB_C; i += TPB) m = fmaxf(m, p[i]);
  red[tid] = m;
  __syncthreads();
  for (int off = TPB / 2; off > 0; off >>= 1) {
    if (tid < off) red[tid] = fmaxf(red[tid], red[tid + off]);
    __syncthreads();
  }
  if (tid == 0) rmaxf[blockIdx.x] = sqrtf(red[0]);
}

// ---- weighted terms: 4 voxels/thread (float4), wave-shuffle reduce ----
__global__ __launch_bounds__(TPB) void k_sums1(const float* __restrict__ d2,
                                               const unsigned* __restrict__ skel,
                                               const float* __restrict__ rmaxf,
                                               double* __restrict__ ps) {
  __shared__ double red[4][4];                   // [wave][term]
  int tid = threadIdx.x;
  int q = blockIdx.x * TPB + tid;                // quad index over NBS/4
  int idx0 = q * 4;
  int b = idx0 / S;                              // S%4==0 -> same b for all 4
  float rmax_p = rmaxf[b];
  float rmax_t = rmaxf[2 + b];
  float4 dp4 = ((const float4*)d2)[q];
  float4 dt4 = ((const float4*)(d2 + NBS))[q];
  unsigned spw = (skel[idx0 >> 5] >> (idx0 & 31)) & 0xFu;
  unsigned stw = (skel[(NBS + idx0) >> 5] >> (idx0 & 31)) & 0xFu;
  double acc[4] = {0.0, 0.0, 0.0, 0.0};
  const float* dp = &dp4.x;
  const float* dt = &dt4.x;
  #pragma unroll
  for (int s = 0; s < 4; ++s) {
    float dist_p = sqrtf(dp[s]);
    float dist_t = sqrtf(dt[s]);
    bool sp = (spw >> s) & 1u;
    bool st = (stw >> s) & 1u;
    float q_vp = (rmax_p > 0.0f) ? dist_p / rmax_p : dist_p;
    float q_vl = (rmax_t > 0.0f) ? dist_t / rmax_t : dist_t;
    float q_spvp = sp ? q_vp : 0.0f;
    float q_slvl = st ? q_vl : 0.0f;
    float q_sp = sp ? (1.0f + EPSf) / (q_spvp * q_spvp + EPSf) : 0.0f;
    float q_sl = st ? (1.0f + EPSf) / (q_slvl * q_slvl + EPSf) : 0.0f;
    acc[0] += (double)(q_sp * q_vl);
    acc[1] += (double)(((q_spvp != 0.0f) && (q_slvl == 0.0f)) ? q_spvp * q_sp
                                                              : q_slvl * q_sp);
    acc[2] += (double)(q_sl * q_vp);
    acc[3] += (double)(((q_slvl != 0.0f) && (q_spvp == 0.0f)) ? q_slvl * q_sl
                                                              : q_spvp * q_sl);
  }
  #pragma unroll
  for (int k = 0; k < 4; ++k)
    #pragma unroll
    for (int o = 32; o > 0; o >>= 1)
      acc[k] += __shfl_xor(acc[k], o, 64);
  int wave = tid >> 6;
  if ((tid & 63) == 0) {
    #pragma unroll
    for (int k = 0; k < 4; ++k) red[wave][k] = acc[k];
  }
  __syncthreads();
  if (tid == 0) {
    #pragma unroll
    for (int k = 0; k < 4; ++k)
      ps[blockIdx.x * 4 + k] = red[0][k] + red[1][k] + red[2][k] + red[3][k];
  }
}

// ---- stage 2: reduce partials per term, compute loss ----
__global__ __launch_bounds__(TPB) void k_sums2(const double* __restrict__ ps,
                                               float* __restrict__ out) {
  __shared__ double red[TPB];
  int tid = threadIdx.x;
  double s[4] = {0.0, 0.0, 0.0, 0.0};
  for (int i = tid; i < BLK_SUMS; i += TPB) {
    s[0] += ps[i * 4 + 0];
    s[1] += ps[i * 4 + 1];
    s[2] += ps[i * 4 + 2];
    s[3] += ps[i * 4 + 3];
  }
  double tot[4];
  #pragma unroll
  for (int k = 0; k < 4; ++k) {
    red[tid] = s[k];
    __syncthreads();
    for (int off = TPB / 2; off > 0; off >>= 1) {
      if (tid < off) red[tid] += red[tid + off];
      __syncthreads();
    }
    if (tid == 0) tot[k] = red[0];
    __syncthreads();
  }
  if (tid == 0) {
    double wp = (tot[0] + 1.0) / (tot[1] + 1.0);
    double ws = (tot[2] + 1.0) / (tot[3] + 1.0);
    out[0] = (float)(1.0 - 2.0 * (wp * ws) / (wp + ws));
  }
}

} // namespace

extern "C" void kernel_launch(void* const* d_in, const int* in_sizes, int n_in,
                              void* d_out, int out_size, void* d_ws, size_t ws_size,
                              hipStream_t stream) {
  (void)in_sizes; (void)n_in; (void)out_size; (void)ws_size;
  const float* logits = (const float*)d_in[0];   // [B,2,D,H,W] f32
  const int* labels   = (const int*)d_in[1];     // [B,1,D,H,W] i32
  float* out = (float*)d_out;

  constexpr int NTW = NT / 32;
  float* D2 = (float*)d_ws;                 // EDT ping
  float* EF = D2 + NT;                      // EDT pong
  unsigned* MB    = (unsigned*)(EF + NT);   // pristine masks (EDT source)
  unsigned* XB    = MB + NTW;               // skeleton x ping
  unsigned* EB    = XB + NTW;               // skeleton x pong
  unsigned* SKELB = EB + NTW;
  float* PMAX  = (float*)(SKELB + NTW);     // 1152 per-block d2 maxes
  double* PS   = (double*)(PMAX + BLK_EDT); // 1152*4 doubles (8B-aligned offset)
  float* RMAXF = (float*)(PS + 4 * BLK_SUMS);

  dim3 blk(TPB);

  k_binarize<<<BLK_NBS, blk, 0, stream>>>(logits, labels, MB);

  // ---- soft skeleton: 11 updates = 5 double-steps + 1 single (6 launches) ----
  k_stepN<2><<<256, blk, 0, stream>>>(MB, XB, SKELB, 1);   // updates k=0,1; X->X2
  k_stepN<2><<<256, blk, 0, stream>>>(XB, EB, SKELB, 0);   // k=2,3;  X2->X4
  k_stepN<2><<<256, blk, 0, stream>>>(EB, XB, SKELB, 0);   // k=4,5;  X4->X6
  k_stepN<2><<<256, blk, 0, stream>>>(XB, EB, SKELB, 0);   // k=6,7;  X6->X8
  k_stepN<2><<<256, blk, 0, stream>>>(EB, XB, SKELB, 0);   // k=8,9;  X8->X10
  k_stepN<1><<<256, blk, 0, stream>>>(XB, EB, SKELB, 0);   // k=10

  // ---- exact EDT: 3 register-blocked min-conv passes ----
  k_edt0<<<BLK_EDT, blk, 0, stream>>>(MB, D2);
  k_edt1<<<BLK_EDT, blk, 0, stream>>>(D2, EF);
  k_edt2<<<BLK_EDT, blk, 0, stream>>>(EF, D2, SKELB, PMAX);

  // ---- rmax stage 2, weighted sums, loss ----
  k_rmax2<<<4, blk, 0, stream>>>(PMAX, RMAXF);
  k_sums1<<<BLK_SUMS, blk, 0, stream>>>(D2, SKELB, RMAXF, PS);
  k_sums2<<<1, blk, 0, stream>>>(PS, out);
}